// Round 4
// baseline (229.446 us; speedup 1.0000x reference)
//
#include <hip/hip_runtime.h>
#include <hip/hip_fp16.h>
#include <cmath>

#define BATCH 8192

typedef short bf16x8 __attribute__((ext_vector_type(8)));
typedef float f32x4 __attribute__((ext_vector_type(4)));

__device__ __forceinline__ float bf2f(unsigned short s){
    return __uint_as_float(((unsigned)s) << 16);
}
__device__ __forceinline__ void split2(float x, unsigned short& h, unsigned short& l){
    unsigned u = __float_as_uint(x);
    unsigned hr = u + 0x7fffu + ((u >> 16) & 1u);
    unsigned short hs = (unsigned short)(hr >> 16);
    float hf = __uint_as_float(((unsigned)hs) << 16);
    float d = x - hf;
    unsigned v = __float_as_uint(d);
    unsigned short ls = (unsigned short)((v + 0x7fffu + ((v >> 16) & 1u)) >> 16);
    h = hs; l = ls;
}
__device__ __forceinline__ float fsig(float x){ return 1.f / (1.f + __expf(-x)); }
__device__ __forceinline__ float ftanh(float x){
    x = fminf(fmaxf(x, -10.f), 10.f);
    const float e = __expf(2.f*x);
    return (e - 1.f) / (e + 1.f);
}
// async global->LDS DMA, 16B per lane; lds dest = wave-uniform base + lane*16
__device__ __forceinline__ void async_copy16(void* lds, const void* g){
    __builtin_amdgcn_global_load_lds(
        (const __attribute__((address_space(1))) unsigned int*)g,
        (__attribute__((address_space(3))) unsigned int*)lds, 16, 0, 0);
}

// ---------------------------------------------------------------------------
// split perception into bf16 hi/lo planes
// ---------------------------------------------------------------------------
__global__ __launch_bounds__(256) void split_pair(
    const float* __restrict__ X, unsigned short* __restrict__ H, unsigned short* __restrict__ L)
{
    const size_t i = (size_t)blockIdx.x*256 + threadIdx.x;
    float4 v = *reinterpret_cast<const float4*>(&X[i*4]);
    unsigned short h0,h1,h2,h3,l0,l1,l2,l3;
    split2(v.x,h0,l0); split2(v.y,h1,l1); split2(v.z,h2,l2); split2(v.w,h3,l3);
    *reinterpret_cast<ushort4*>(&H[i*4]) = make_ushort4(h0,h1,h2,h3);
    *reinterpret_cast<ushort4*>(&L[i*4]) = make_ushort4(l0,l1,l2,l3);
}

// ---------------------------------------------------------------------------
// All weight preprocessing in one launch.
//  bx 0..15 : Wf = in_proj @ W_in (1024x512, K=256), rows<512 *conv3 -> W1 pair
//  bx 16/17 : Wt = [mu_w;ls_w] @ out_proj (128x512) -> Wt pair
//  bx 18    : b1[n] = in_proj[n,:].b_in (*conv3+conv_b for n<512)
//  bx 19    : split x_proj (48x512) -> Xp pair, rows 48..63 zeroed
// ---------------------------------------------------------------------------
__global__ __launch_bounds__(256) void prep_all(
    const float* __restrict__ in_proj, const float* __restrict__ W_in,
    const float* __restrict__ b_in,
    const float* __restrict__ mu_w, const float* __restrict__ ls_w,
    const float* __restrict__ conv_w, const float* __restrict__ conv_b,
    const float* __restrict__ out_proj, const float* __restrict__ x_proj,
    unsigned short* __restrict__ W1h, unsigned short* __restrict__ W1l,
    unsigned short* __restrict__ Wth, unsigned short* __restrict__ Wtl,
    unsigned short* __restrict__ Xph, unsigned short* __restrict__ Xpl,
    float* __restrict__ b1)
{
    const int bx = blockIdx.x, by = blockIdx.y;
    const int tid = threadIdx.x;
    if (bx == 18){
        if (by) return;
        for (int p=0;p<4;p++){
            const int n = tid + p*256;
            float acc = 0.f;
            for (int j=0;j<256;j++) acc = fmaf(in_proj[n*256+j], b_in[j], acc);
            b1[n] = (n < 512) ? fmaf(acc, conv_w[n*4+3], conv_b[n]) : acc;
        }
        return;
    }
    if (bx == 19){
        const int n0 = by*64;
#pragma unroll
        for (int p=0;p<16;p++){
            const int idx = p*256 + tid;        // 0..4095
            const int r = idx >> 6;             // 0..63
            const int c = n0 + (idx & 63);
            const float v = (r < 48) ? x_proj[(size_t)r*512 + c] : 0.f;
            unsigned short h,l; split2(v,h,l);
            Xph[(size_t)r*512+c]=h; Xpl[(size_t)r*512+c]=l;
        }
        return;
    }
    const float* A; unsigned short *Oh, *Ol; int m0; bool doscale;
    const float* B;
    if (bx < 16){ A = in_proj + (size_t)bx*64*256; B = W_in; Oh=W1h; Ol=W1l; m0=bx*64; doscale=true; }
    else { A = (bx==16 ? mu_w : ls_w); B = out_proj; Oh=Wth; Ol=Wtl; m0=(bx-16)*64; doscale=false; }
    const int n0 = by*64;

    __shared__ float As[16][68];
    __shared__ float Ws[16][68];
    const int tm = tid/16, tn = tid%16;
    float acc[4][4];
#pragma unroll
    for (int i=0;i<4;i++)
#pragma unroll
      for (int j=0;j<4;j++) acc[i][j]=0.f;

    for (int k0=0;k0<256;k0+=16){
        {
            const int kf = tid & 3, mm = tid >> 2;
            float4 v = *reinterpret_cast<const float4*>(A + (size_t)mm*256 + k0 + kf*4);
            As[kf*4+0][mm]=v.x; As[kf*4+1][mm]=v.y; As[kf*4+2][mm]=v.z; As[kf*4+3][mm]=v.w;
        }
        {
            const int nn4 = tid & 15, kk = tid >> 4;
            float4 v = *reinterpret_cast<const float4*>(B + (size_t)(k0+kk)*512 + n0 + nn4*4);
            *reinterpret_cast<float4*>(&Ws[kk][nn4*4]) = v;
        }
        __syncthreads();
#pragma unroll
        for (int k=0;k<16;k++){
            const float4 av = *reinterpret_cast<const float4*>(&As[k][tm*4]);
            const float4 bv = *reinterpret_cast<const float4*>(&Ws[k][tn*4]);
            float a[4]={av.x,av.y,av.z,av.w}, b[4]={bv.x,bv.y,bv.z,bv.w};
#pragma unroll
            for (int i=0;i<4;i++)
#pragma unroll
                for (int j=0;j<4;j++) acc[i][j] = fmaf(a[i], b[j], acc[i][j]);
        }
        __syncthreads();
    }
#pragma unroll
    for (int i=0;i<4;i++){
        const int gm = m0 + tm*4 + i;
        const float s = (doscale && gm < 512) ? conv_w[gm*4+3] : 1.f;
        const int n = n0 + tn*4;
        unsigned short h[4], l[4];
#pragma unroll
        for (int j=0;j<4;j++) split2(acc[i][j]*s, h[j], l[j]);
        *reinterpret_cast<ushort4*>(&Oh[(size_t)gm*512 + n]) = make_ushort4(h[0],h[1],h[2],h[3]);
        *reinterpret_cast<ushort4*>(&Ol[(size_t)gm*512 + n]) = make_ushort4(l[0],l[1],l[2],l[3]);
    }
}

// ---------------------------------------------------------------------------
// bf16x3 MFMA GEMM (16x16x32) with global_load_lds staging.
// A/B are bf16 hi/lo plane pairs, both T x K row-major (K mult of 32).
// LDS chunk order f = r*T + m  ==  fragment layout [q-plane][row][8].
// EPI 0: fp32 store O0[row*ldc+col] for col<ncols
// EPI 1: col<512: u=silu(v+bias[col]) -> split -> Uh/Ul (stride 512);
//        col>=512: Zh[row*512+col-512] = fp16(v+bias[col])
// EPI 2: col<64: O0[row*64+col]=tanh(v+e0[col]); else O1=clip(v+e1[col-64],-5,2)
// ---------------------------------------------------------------------------
template<int TM,int TN,int WM,int WN,int EPI>
__global__ __launch_bounds__(256) void mgemm(
    const unsigned short* __restrict__ Ah_g, const unsigned short* __restrict__ Al_g,
    const unsigned short* __restrict__ Bh_g, const unsigned short* __restrict__ Bl_g,
    const float* __restrict__ bias,
    const float* __restrict__ e0, const float* __restrict__ e1,
    unsigned short* __restrict__ Uh, unsigned short* __restrict__ Ul,
    __half* __restrict__ Zh,
    float* __restrict__ O0, float* __restrict__ O1,
    int K, int ldc, int ncols)
{
    constexpr int WAVES_N = TN/WN;
    constexpr int MT = WM/16, NT = WN/16;
    constexpr int ACH = 4*TM, BCH = 4*TN;    // 16B chunks per plane
    __shared__ unsigned short sm[(2*ACH + 2*BCH)*8];
    unsigned short* const Als = sm + ACH*8;
    unsigned short* const Bhs = sm + 2*ACH*8;
    unsigned short* const Bls = sm + 2*ACH*8 + BCH*8;

    const int tid = threadIdx.x;
    const int m0 = blockIdx.x * TM;
    const int n0 = blockIdx.y * TN;
    const int lane = tid & 63, wid = tid >> 6;
    const int quad = lane >> 4, l16 = lane & 15;
    const int wm = (wid / WAVES_N) * WM;
    const int wn = (wid % WAVES_N) * WN;

    f32x4 acc[MT][NT];
#pragma unroll
    for (int i=0;i<MT;i++)
#pragma unroll
      for (int j=0;j<NT;j++) acc[i][j] = (f32x4){0.f,0.f,0.f,0.f};

    for (int k0=0; k0<K; k0+=32){
#pragma unroll
        for (int it=0; it<TM/64; ++it){
            const int f = it*256 + tid;
            const int m = f & (TM-1);
            const int r = f / TM;
            const size_t g = (size_t)(m0+m)*K + k0 + r*8;
            const int wb = (it*256 + wid*64)*8;      // wave-uniform base (shorts)
            async_copy16(sm  + wb, Ah_g + g);
            async_copy16(Als + wb, Al_g + g);
        }
#pragma unroll
        for (int it=0; it<TN/64; ++it){
            const int f = it*256 + tid;
            const int n = f & (TN-1);
            const int r = f / TN;
            const size_t g = (size_t)(n0+n)*K + k0 + r*8;
            const int wb = (it*256 + wid*64)*8;
            async_copy16(Bhs + wb, Bh_g + g);
            async_copy16(Bls + wb, Bl_g + g);
        }
        __syncthreads();

        bf16x8 ah[MT], al[MT], bh[NT], bl[NT];
#pragma unroll
        for (int mt=0; mt<MT; ++mt){
            const int off = (quad*TM + wm + mt*16 + l16)*8;
            ah[mt] = *reinterpret_cast<const bf16x8*>(&sm [off]);
            al[mt] = *reinterpret_cast<const bf16x8*>(&Als[off]);
        }
#pragma unroll
        for (int nt=0; nt<NT; ++nt){
            const int off = (quad*TN + wn + nt*16 + l16)*8;
            bh[nt] = *reinterpret_cast<const bf16x8*>(&Bhs[off]);
            bl[nt] = *reinterpret_cast<const bf16x8*>(&Bls[off]);
        }
#pragma unroll
        for (int mt=0; mt<MT; ++mt)
#pragma unroll
        for (int nt=0; nt<NT; ++nt){
            acc[mt][nt] = __builtin_amdgcn_mfma_f32_16x16x32_bf16(ah[mt], bh[nt], acc[mt][nt], 0,0,0);
            acc[mt][nt] = __builtin_amdgcn_mfma_f32_16x16x32_bf16(al[mt], bh[nt], acc[mt][nt], 0,0,0);
            acc[mt][nt] = __builtin_amdgcn_mfma_f32_16x16x32_bf16(ah[mt], bl[nt], acc[mt][nt], 0,0,0);
        }
        __syncthreads();
    }

    // C/D layout: col=lane&15, row=quad*4+reg  [m89]
#pragma unroll
    for (int mt=0; mt<MT; ++mt)
#pragma unroll
    for (int nt=0; nt<NT; ++nt)
#pragma unroll
    for (int r=0; r<4; ++r){
        const int row = m0 + wm + mt*16 + quad*4 + r;
        const int col = n0 + wn + nt*16 + l16;
        float v = acc[mt][nt][r];
        if (EPI==0){
            if (col < ncols) O0[(size_t)row*ldc + col] = v;
        } else if (EPI==1){
            v += bias[col];
            if (col < 512){
                const float us = v * fsig(v);
                unsigned short h,l; split2(us,h,l);
                const size_t off = (size_t)row*512 + col;
                Uh[off]=h; Ul[off]=l;
            } else {
                Zh[(size_t)row*512 + (col-512)] = __float2half(v);
            }
        } else {
            if (col < 64){
                O0[(size_t)row*64 + col] = ftanh(v + e0[col]);
            } else {
                O1[(size_t)row*64 + (col-64)] = fminf(fmaxf(v + e1[col-64], -5.f), 2.f);
            }
        }
    }
}

// ---------------------------------------------------------------------------
// SSM elementwise. Thread owns one d (dtw[d] in 16 regs); xdbl row values are
// wave-uniform (scalar K$ loads). 32 rows per block, grid (B/32, 2).
// y = u*(softplus(dt.dtw_d+dtb_d)*(B.C)+Dskip_d)*silu(z) -> bf16 pair
// ---------------------------------------------------------------------------
__global__ __launch_bounds__(256) void ssm_ew2(
    const float* __restrict__ xdbl,      // (B,48): dt[0:16] Bm[16:32] Cm[32:48]
    const unsigned short* __restrict__ Uh, const unsigned short* __restrict__ Ul,
    const __half* __restrict__ Zh,
    const float* __restrict__ dtw, const float* __restrict__ dtb,
    const float* __restrict__ dskip,
    unsigned short* __restrict__ Yh, unsigned short* __restrict__ Yl)
{
    const int tid = threadIdx.x;
    const int m0 = blockIdx.x * 32;
    const int d  = blockIdx.y * 256 + tid;
    float w[16];
#pragma unroll
    for (int j=0;j<4;j++){
        const float4 v = *reinterpret_cast<const float4*>(&dtw[d*16 + j*4]);
        w[j*4]=v.x; w[j*4+1]=v.y; w[j*4+2]=v.z; w[j*4+3]=v.w;
    }
    const float db = dtb[d], dk = dskip[d];
#pragma unroll 2
    for (int r=0;r<32;r++){
        const float* xr = xdbl + (size_t)(m0+r)*48;   // uniform -> scalar loads
        float bc = 0.f;
#pragma unroll
        for (int n=0;n<16;n++) bc = fmaf(xr[16+n], xr[32+n], bc);
        float dtv = db;
#pragma unroll
        for (int j=0;j<16;j++) dtv = fmaf(xr[j], w[j], dtv);
        const float delta = (dtv > 20.f) ? dtv : __logf(1.f + __expf(dtv));
        const size_t off = (size_t)(m0+r)*512 + d;
        const float u = bf2f(Uh[off]) + bf2f(Ul[off]);
        const float z = __half2float(Zh[off]);
        float y = u * fmaf(delta, bc, dk);
        y *= z * fsig(z);
        unsigned short h,l; split2(y,h,l);
        Yh[off]=h; Yl[off]=l;
    }
}

extern "C" void kernel_launch(void* const* d_in, const int* in_sizes, int n_in,
                              void* d_out, int out_size, void* d_ws, size_t ws_size,
                              hipStream_t stream) {
    (void)in_sizes; (void)n_in; (void)out_size; (void)ws_size;
    const float* percep  = (const float*)d_in[0];
    const float* W_in    = (const float*)d_in[1];
    const float* b_in    = (const float*)d_in[2];
    const float* mu_w    = (const float*)d_in[3];
    const float* mu_b    = (const float*)d_in[4];
    const float* ls_w    = (const float*)d_in[5];
    const float* ls_b    = (const float*)d_in[6];
    const float* in_proj = (const float*)d_in[7];
    const float* conv_w  = (const float*)d_in[8];
    const float* conv_b  = (const float*)d_in[9];
    const float* x_proj  = (const float*)d_in[10];
    const float* dt_w    = (const float*)d_in[11];
    const float* dt_b    = (const float*)d_in[12];
    // d_in[13] A_log unused at L=1 (h0=0)
    const float* Dskip   = (const float*)d_in[14];
    const float* out_proj= (const float*)d_in[15];

    char* ws = (char*)d_ws;
    const size_t MB = 1u<<20;
    unsigned short* W1h = (unsigned short*)(ws);
    unsigned short* W1l = (unsigned short*)(ws + 1*MB);
    unsigned short* Wth = (unsigned short*)(ws + 2*MB);
    unsigned short* Wtl = (unsigned short*)(ws + 2*MB + 128*1024);
    unsigned short* Xph = (unsigned short*)(ws + 2*MB + 256*1024);
    unsigned short* Xpl = (unsigned short*)(ws + 2*MB + 320*1024);
    float*          b1  = (float*)         (ws + 2*MB + 384*1024);
    float*          xdbl= (float*)         (ws + 3*MB);   // 1.5 MB
    unsigned short* Ph  = (unsigned short*)(ws + 5*MB);
    unsigned short* Pl  = (unsigned short*)(ws + 13*MB);
    unsigned short* Uh  = (unsigned short*)(ws + 21*MB);
    unsigned short* Ul  = (unsigned short*)(ws + 29*MB);
    __half*         Zh  = (__half*)        (ws + 37*MB);
    unsigned short* Yh  = (unsigned short*)(ws + 45*MB);
    unsigned short* Yl  = (unsigned short*)(ws + 53*MB);

    float* mu_o = (float*)d_out;
    float* ls_o = (float*)d_out + (size_t)BATCH*64;

    dim3 blk(256);
    split_pair<<<dim3(BATCH*512/1024), blk, 0, stream>>>(percep, Ph, Pl);
    prep_all<<<dim3(20,8), blk, 0, stream>>>(
        in_proj, W_in, b_in, mu_w, ls_w, conv_w, conv_b, out_proj, x_proj,
        W1h, W1l, Wth, Wtl, Xph, Xpl, b1);
    // K1: xz = p @ Wf.T + b1; u=silu -> U pair; z -> Zh fp16
    mgemm<128,128,64,64,1><<<dim3(64,8), blk, 0, stream>>>(
        Ph, Pl, W1h, W1l, b1, nullptr, nullptr, Uh, Ul, Zh, nullptr, nullptr, 512, 0, 0);
    // G2a: xdbl = u @ x_proj.T  (N=48 padded to 64)
    mgemm<64,64,32,32,0><<<dim3(128,1), blk, 0, stream>>>(
        Uh, Ul, Xph, Xpl, nullptr, nullptr, nullptr, nullptr, nullptr, nullptr,
        xdbl, nullptr, 512, 48, 48);
    // EW: y -> Y pair
    ssm_ew2<<<dim3(BATCH/32, 2), blk, 0, stream>>>(
        xdbl, Uh, Ul, Zh, dt_w, dt_b, Dskip, Yh, Yl);
    // K4: [mu|ls] = act(y @ Wt.T + b)
    mgemm<64,64,32,32,2><<<dim3(128,2), blk, 0, stream>>>(
        Yh, Yl, Wth, Wtl, nullptr, mu_b, ls_b, nullptr, nullptr, nullptr,
        mu_o, ls_o, 512, 0, 0);
}

// Round 5
// 220.442 us; speedup vs baseline: 1.0408x; 1.0408x over previous
//
#include <hip/hip_runtime.h>
#include <cmath>

#define BATCH 8192

typedef short bf16x8 __attribute__((ext_vector_type(8)));
typedef float f32x4 __attribute__((ext_vector_type(4)));

__device__ __forceinline__ void split2(float x, unsigned short& h, unsigned short& l){
    unsigned u = __float_as_uint(x);
    unsigned hr = u + 0x7fffu + ((u >> 16) & 1u);
    unsigned short hs = (unsigned short)(hr >> 16);
    float hf = __uint_as_float(((unsigned)hs) << 16);
    float d = x - hf;
    unsigned v = __float_as_uint(d);
    unsigned short ls = (unsigned short)((v + 0x7fffu + ((v >> 16) & 1u)) >> 16);
    h = hs; l = ls;
}
__device__ __forceinline__ float fsig(float x){ return 1.f / (1.f + __expf(-x)); }
__device__ __forceinline__ float ftanh(float x){
    x = fminf(fmaxf(x, -10.f), 10.f);
    const float e = __expf(2.f*x);
    return (e - 1.f) / (e + 1.f);
}
__device__ __forceinline__ void async_copy16(void* lds, const void* g){
    __builtin_amdgcn_global_load_lds(
        (const __attribute__((address_space(1))) unsigned int*)g,
        (__attribute__((address_space(3))) unsigned int*)lds, 16, 0, 0);
}

// ---------------------------------------------------------------------------
// All weight preprocessing in one launch.
//  bx 0..15 : Wf = in_proj @ W_in (1024x512, K=256), rows<512 *conv3 -> W1 pair
//  bx 16/17 : Wt = [mu_w;ls_w] @ out_proj (128x512) -> Wt pair
//  bx 18    : b1[n] = in_proj[n,:].b_in (*conv3+conv_b for n<512)
//  bx 19    : split x_proj (48x512) -> Xp pair, rows 48..63 zeroed
// ---------------------------------------------------------------------------
__global__ __launch_bounds__(256) void prep_all(
    const float* __restrict__ in_proj, const float* __restrict__ W_in,
    const float* __restrict__ b_in,
    const float* __restrict__ mu_w, const float* __restrict__ ls_w,
    const float* __restrict__ conv_w, const float* __restrict__ conv_b,
    const float* __restrict__ out_proj, const float* __restrict__ x_proj,
    unsigned short* __restrict__ W1h, unsigned short* __restrict__ W1l,
    unsigned short* __restrict__ Wth, unsigned short* __restrict__ Wtl,
    unsigned short* __restrict__ Xph, unsigned short* __restrict__ Xpl,
    float* __restrict__ b1)
{
    const int bx = blockIdx.x, by = blockIdx.y;
    const int tid = threadIdx.x;
    if (bx == 18){
        if (by) return;
        for (int p=0;p<4;p++){
            const int n = tid + p*256;
            float acc = 0.f;
            for (int j=0;j<256;j++) acc = fmaf(in_proj[n*256+j], b_in[j], acc);
            b1[n] = (n < 512) ? fmaf(acc, conv_w[n*4+3], conv_b[n]) : acc;
        }
        return;
    }
    if (bx == 19){
        const int n0 = by*64;
#pragma unroll
        for (int p=0;p<16;p++){
            const int idx = p*256 + tid;
            const int r = idx >> 6;
            const int c = n0 + (idx & 63);
            const float v = (r < 48) ? x_proj[(size_t)r*512 + c] : 0.f;
            unsigned short h,l; split2(v,h,l);
            Xph[(size_t)r*512+c]=h; Xpl[(size_t)r*512+c]=l;
        }
        return;
    }
    const float* A; unsigned short *Oh, *Ol; int m0; bool doscale;
    const float* B;
    if (bx < 16){ A = in_proj + (size_t)bx*64*256; B = W_in; Oh=W1h; Ol=W1l; m0=bx*64; doscale=true; }
    else { A = (bx==16 ? mu_w : ls_w); B = out_proj; Oh=Wth; Ol=Wtl; m0=(bx-16)*64; doscale=false; }
    const int n0 = by*64;

    __shared__ float As[16][68];
    __shared__ float Ws[16][68];
    const int tm = tid/16, tn = tid%16;
    float acc[4][4];
#pragma unroll
    for (int i=0;i<4;i++)
#pragma unroll
      for (int j=0;j<4;j++) acc[i][j]=0.f;

    for (int k0=0;k0<256;k0+=16){
        {
            const int kf = tid & 3, mm = tid >> 2;
            float4 v = *reinterpret_cast<const float4*>(A + (size_t)mm*256 + k0 + kf*4);
            As[kf*4+0][mm]=v.x; As[kf*4+1][mm]=v.y; As[kf*4+2][mm]=v.z; As[kf*4+3][mm]=v.w;
        }
        {
            const int nn4 = tid & 15, kk = tid >> 4;
            float4 v = *reinterpret_cast<const float4*>(B + (size_t)(k0+kk)*512 + n0 + nn4*4);
            *reinterpret_cast<float4*>(&Ws[kk][nn4*4]) = v;
        }
        __syncthreads();
#pragma unroll
        for (int k=0;k<16;k++){
            const float4 av = *reinterpret_cast<const float4*>(&As[k][tm*4]);
            const float4 bv = *reinterpret_cast<const float4*>(&Ws[k][tn*4]);
            float a[4]={av.x,av.y,av.z,av.w}, b[4]={bv.x,bv.y,bv.z,bv.w};
#pragma unroll
            for (int i=0;i<4;i++)
#pragma unroll
                for (int j=0;j<4;j++) acc[i][j] = fmaf(a[i], b[j], acc[i][j]);
        }
        __syncthreads();
    }
#pragma unroll
    for (int i=0;i<4;i++){
        const int gm = m0 + tm*4 + i;
        const float s = (doscale && gm < 512) ? conv_w[gm*4+3] : 1.f;
        const int n = n0 + tn*4;
        unsigned short h[4], l[4];
#pragma unroll
        for (int j=0;j<4;j++) split2(acc[i][j]*s, h[j], l[j]);
        *reinterpret_cast<ushort4*>(&Oh[(size_t)gm*512 + n]) = make_ushort4(h[0],h[1],h[2],h[3]);
        *reinterpret_cast<ushort4*>(&Ol[(size_t)gm*512 + n]) = make_ushort4(l[0],l[1],l[2],l[3]);
    }
}

// ---------------------------------------------------------------------------
// bf16x3 MFMA GEMM, double-buffered, 1 barrier per k-step.
// A: M x K fp32 (manually split to bf16 hi/lo in-register -> ds_write).
// B: N x K bf16 hi/lo plane pair, staged via global_load_lds (16B DMA).
// LDS chunk order f = r*T + m  ==  fragment layout [q-plane][row][8].
// EPI 0: O0[row*ldc+col] = v for col<ncols (fp32)
// EPI 1: col<512: Uf = silu(v+bias[col]); col>=512: Zf = v+bias[col]  (fp32)
// EPI 2: col<64: O0=tanh(v+e0[col]); else O1=clip(v+e1[col-64],-5,2)
// ---------------------------------------------------------------------------
template<int TM,int TN,int WM,int WN,int EPI>
__global__ __launch_bounds__(256,2) void mgemm2(
    const float* __restrict__ A,
    const unsigned short* __restrict__ Bh_g, const unsigned short* __restrict__ Bl_g,
    const float* __restrict__ bias,
    const float* __restrict__ e0, const float* __restrict__ e1,
    float* __restrict__ O0, float* __restrict__ O1,
    int K, int ldc, int ncols)
{
    constexpr int WAVES_N = TN/WN;
    constexpr int MT = WM/16, NT = WN/16;
    constexpr int ACH = 4*TM, BCH = 4*TN;      // 16B chunks per plane per buffer
    constexpr int BUF = (2*ACH + 2*BCH)*8;     // shorts per buffer
    constexpr int IA = ACH/256, IB = BCH/256;
    __shared__ unsigned short sm[2*BUF];

    const int tid = threadIdx.x;
    const int m0 = blockIdx.x * TM;
    const int n0 = blockIdx.y * TN;
    const int lane = tid & 63, wid = tid >> 6;
    const int quad = lane >> 4, l16 = lane & 15;
    const int wm = (wid / WAVES_N) * WM;
    const int wn = (wid % WAVES_N) * WN;
    const int NK = K >> 5;

    f32x4 acc[MT][NT];
#pragma unroll
    for (int i=0;i<MT;i++)
#pragma unroll
      for (int j=0;j<NT;j++) acc[i][j] = (f32x4){0.f,0.f,0.f,0.f};

    float4 areg[IA*2];

    auto loadA = [&](int k){
#pragma unroll
        for (int it=0; it<IA; ++it){
            const int f = it*256 + tid;
            const int m = f % TM, r = f / TM;
            const float* src = A + (size_t)(m0+m)*K + k*32 + r*8;
            areg[it*2]   = *reinterpret_cast<const float4*>(src);
            areg[it*2+1] = *reinterpret_cast<const float4*>(src+4);
        }
    };
    auto dmaB = [&](int k, int b){
        unsigned short* dst = sm + b*BUF + 2*ACH*8;
#pragma unroll
        for (int it=0; it<IB; ++it){
            const int f = it*256 + tid;
            const int n = f % TN, r = f / TN;
            const size_t g = (size_t)(n0+n)*K + k*32 + r*8;
            const int wb = (it*256 + wid*64)*8;
            async_copy16(dst + wb, Bh_g + g);
            async_copy16(dst + BCH*8 + wb, Bl_g + g);
        }
    };
    auto writeA = [&](int b){
        unsigned short* dh = sm + b*BUF;
        unsigned short* dl = dh + ACH*8;
#pragma unroll
        for (int it=0; it<IA; ++it){
            const int f = it*256 + tid;
            const float* p = reinterpret_cast<const float*>(&areg[it*2]);
            unsigned short h[8], l[8];
#pragma unroll
            for (int j=0;j<8;j++) split2(p[j], h[j], l[j]);
            uint4 H, L;
            H.x=(unsigned)h[0]|((unsigned)h[1]<<16); H.y=(unsigned)h[2]|((unsigned)h[3]<<16);
            H.z=(unsigned)h[4]|((unsigned)h[5]<<16); H.w=(unsigned)h[6]|((unsigned)h[7]<<16);
            L.x=(unsigned)l[0]|((unsigned)l[1]<<16); L.y=(unsigned)l[2]|((unsigned)l[3]<<16);
            L.z=(unsigned)l[4]|((unsigned)l[5]<<16); L.w=(unsigned)l[6]|((unsigned)l[7]<<16);
            *reinterpret_cast<uint4*>(&dh[f*8]) = H;
            *reinterpret_cast<uint4*>(&dl[f*8]) = L;
        }
    };

    // prologue: stage k=0 into buffer 0
    loadA(0); dmaB(0, 0); writeA(0);

    for (int k=0; k<NK; ++k){
        const int cur = k & 1, nxt = cur ^ 1;
        __syncthreads();                      // buf[cur] complete; buf[nxt] free
        const bool pf = (k+1 < NK);
        if (pf){ loadA(k+1); dmaB(k+1, nxt); }

        const unsigned short* bufc = sm + cur*BUF;
        bf16x8 ah[MT], al[MT], bh[NT], bl[NT];
#pragma unroll
        for (int mt=0; mt<MT; ++mt){
            const int off = (quad*TM + wm + mt*16 + l16)*8;
            ah[mt] = *reinterpret_cast<const bf16x8*>(&bufc[off]);
            al[mt] = *reinterpret_cast<const bf16x8*>(&bufc[ACH*8 + off]);
        }
#pragma unroll
        for (int nt=0; nt<NT; ++nt){
            const int off = (quad*TN + wn + nt*16 + l16)*8;
            bh[nt] = *reinterpret_cast<const bf16x8*>(&bufc[2*ACH*8 + off]);
            bl[nt] = *reinterpret_cast<const bf16x8*>(&bufc[2*ACH*8 + BCH*8 + off]);
        }
        // pass-major: 16 independent accumulators between dependent updates
#pragma unroll
        for (int mt=0; mt<MT; ++mt)
#pragma unroll
        for (int nt=0; nt<NT; ++nt)
            acc[mt][nt] = __builtin_amdgcn_mfma_f32_16x16x32_bf16(ah[mt], bh[nt], acc[mt][nt], 0,0,0);
#pragma unroll
        for (int mt=0; mt<MT; ++mt)
#pragma unroll
        for (int nt=0; nt<NT; ++nt)
            acc[mt][nt] = __builtin_amdgcn_mfma_f32_16x16x32_bf16(al[mt], bh[nt], acc[mt][nt], 0,0,0);
#pragma unroll
        for (int mt=0; mt<MT; ++mt)
#pragma unroll
        for (int nt=0; nt<NT; ++nt)
            acc[mt][nt] = __builtin_amdgcn_mfma_f32_16x16x32_bf16(ah[mt], bl[nt], acc[mt][nt], 0,0,0);

        if (pf) writeA(nxt);
    }

    // C/D layout: col=lane&15, row=quad*4+reg  [m89]
#pragma unroll
    for (int mt=0; mt<MT; ++mt)
#pragma unroll
    for (int nt=0; nt<NT; ++nt)
#pragma unroll
    for (int r=0; r<4; ++r){
        const int row = m0 + wm + mt*16 + quad*4 + r;
        const int col = n0 + wn + nt*16 + l16;
        float v = acc[mt][nt][r];
        if (EPI==0){
            if (col < ncols) O0[(size_t)row*ldc + col] = v;
        } else if (EPI==1){
            v += bias[col];
            if (col < 512) O0[(size_t)row*512 + col] = v * fsig(v);
            else           O1[(size_t)row*512 + (col-512)] = v;
        } else {
            if (col < 64) O0[(size_t)row*64 + col] = ftanh(v + e0[col]);
            else          O1[(size_t)row*64 + (col-64)] = fminf(fmaxf(v + e1[col-64], -5.f), 2.f);
        }
    }
}

// ---------------------------------------------------------------------------
// SSM elementwise: thread owns d (dtw[d] in regs), loops 32 rows.
// xdbl row accesses are block-uniform -> scalar loads. All fp32.
// y = u*(softplus(dt.dtw_d+dtb_d)*(B.C)+Dskip_d)*silu(z)
// ---------------------------------------------------------------------------
__global__ __launch_bounds__(256) void ssm_ew3(
    const float* __restrict__ xdbl,      // (B,48): dt[0:16] Bm[16:32] Cm[32:48]
    const float* __restrict__ Uf, const float* __restrict__ Zf,
    const float* __restrict__ dtw, const float* __restrict__ dtb,
    const float* __restrict__ dskip,
    float* __restrict__ Yf)
{
    const int tid = threadIdx.x;
    const int m0 = blockIdx.x * 32;
    const int d  = blockIdx.y * 256 + tid;
    float w[16];
#pragma unroll
    for (int j=0;j<4;j++){
        const float4 v = *reinterpret_cast<const float4*>(&dtw[d*16 + j*4]);
        w[j*4]=v.x; w[j*4+1]=v.y; w[j*4+2]=v.z; w[j*4+3]=v.w;
    }
    const float db = dtb[d], dk = dskip[d];
#pragma unroll 2
    for (int r=0;r<32;r++){
        const float* xr = xdbl + (size_t)(m0+r)*48;
        float bc = 0.f;
#pragma unroll
        for (int n=0;n<16;n++) bc = fmaf(xr[16+n], xr[32+n], bc);
        float dtv = db;
#pragma unroll
        for (int j=0;j<16;j++) dtv = fmaf(xr[j], w[j], dtv);
        const float delta = (dtv > 20.f) ? dtv : __logf(1.f + __expf(dtv));
        const size_t off = (size_t)(m0+r)*512 + d;
        const float u = Uf[off];
        const float z = Zf[off];
        Yf[off] = u * fmaf(delta, bc, dk) * (z * fsig(z));
    }
}

extern "C" void kernel_launch(void* const* d_in, const int* in_sizes, int n_in,
                              void* d_out, int out_size, void* d_ws, size_t ws_size,
                              hipStream_t stream) {
    (void)in_sizes; (void)n_in; (void)out_size; (void)ws_size;
    const float* percep  = (const float*)d_in[0];
    const float* W_in    = (const float*)d_in[1];
    const float* b_in    = (const float*)d_in[2];
    const float* mu_w    = (const float*)d_in[3];
    const float* mu_b    = (const float*)d_in[4];
    const float* ls_w    = (const float*)d_in[5];
    const float* ls_b    = (const float*)d_in[6];
    const float* in_proj = (const float*)d_in[7];
    const float* conv_w  = (const float*)d_in[8];
    const float* conv_b  = (const float*)d_in[9];
    const float* x_proj  = (const float*)d_in[10];
    const float* dt_w    = (const float*)d_in[11];
    const float* dt_b    = (const float*)d_in[12];
    // d_in[13] A_log unused at L=1 (h0=0)
    const float* Dskip   = (const float*)d_in[14];
    const float* out_proj= (const float*)d_in[15];

    char* ws = (char*)d_ws;
    const size_t MB = 1u<<20;
    unsigned short* W1h = (unsigned short*)(ws);                      // 1 MB
    unsigned short* W1l = (unsigned short*)(ws + 1*MB);               // 1 MB
    unsigned short* Wth = (unsigned short*)(ws + 2*MB);               // 128 KB
    unsigned short* Wtl = (unsigned short*)(ws + 2*MB + 128*1024);    // 128 KB
    unsigned short* Xph = (unsigned short*)(ws + 2*MB + 256*1024);    // 64 KB
    unsigned short* Xpl = (unsigned short*)(ws + 2*MB + 320*1024);    // 64 KB
    float*          b1  = (float*)         (ws + 2*MB + 384*1024);    // 4 KB
    float*          xdbl= (float*)         (ws + 3*MB);               // 1.5 MB
    float*          Uf  = (float*)         (ws + 5*MB);               // 16 MB
    float*          Zf  = (float*)         (ws + 21*MB);              // 16 MB
    float*          Yf  = (float*)         (ws + 37*MB);              // 16 MB

    float* mu_o = (float*)d_out;
    float* ls_o = (float*)d_out + (size_t)BATCH*64;

    dim3 blk(256);
    prep_all<<<dim3(20,8), blk, 0, stream>>>(
        in_proj, W_in, b_in, mu_w, ls_w, conv_w, conv_b, out_proj, x_proj,
        W1h, W1l, Wth, Wtl, Xph, Xpl, b1);
    // K1: xz = p @ Wf.T + b1; u=silu -> Uf; z -> Zf
    mgemm2<128,128,64,64,1><<<dim3(64,8), blk, 0, stream>>>(
        percep, W1h, W1l, b1, nullptr, nullptr, Uf, Zf, 512, 0, 0);
    // G2a: xdbl = u @ x_proj.T  (N=48 padded to 64)
    mgemm2<64,64,32,32,0><<<dim3(128,1), blk, 0, stream>>>(
        Uf, Xph, Xpl, nullptr, nullptr, nullptr, xdbl, nullptr, 512, 48, 48);
    // EW: y
    ssm_ew3<<<dim3(BATCH/32, 2), blk, 0, stream>>>(
        xdbl, Uf, Zf, dt_w, dt_b, Dskip, Yf);
    // K4: [mu|ls] = act(y @ Wt.T + b)
    mgemm2<64,64,32,32,2><<<dim3(128,2), blk, 0, stream>>>(
        Yf, Wth, Wtl, nullptr, mu_b, ls_b, mu_o, ls_o, 512, 0, 0);
}